// Round 2
// baseline (479.227 us; speedup 1.0000x reference)
//
#include <hip/hip_runtime.h>

#define B_    256
#define N_    256
#define DIN   768
#define DOUT  300
#define DOUTP 320           // padded to 20*16
#define DOUTC 160           // cols per gemm1 block (col-split by 2)
#define M_    (B_*N_)       // 65536
#define HP_ELEMS (M_*DOUT)  // 19660800
#define NEG_INF -9.0e15f

typedef _Float16 f16;
typedef __attribute__((ext_vector_type(8))) _Float16 f16x8;
typedef __attribute__((ext_vector_type(4))) _Float16 f16x4;
typedef __attribute__((ext_vector_type(4))) float    f32x4;

__device__ __forceinline__ void async_copy16(void* lds, const void* g) {
    __builtin_amdgcn_global_load_lds(
        (const __attribute__((address_space(1))) void*)g,
        (__attribute__((address_space(3))) void*)lds, 16, 0, 0);
}

#define STR_(x) #x
#define STR(x) STR_(x)

// ---------------- kernel 0: Wt[n][k] = f16(W[k][n]), zero-pad n>=300 -------
__global__ __launch_bounds__(256) void prep_wt(const float* __restrict__ W,
                                               f16* __restrict__ Wt) {
    int idx = blockIdx.x * 256 + threadIdx.x;      // over DOUTP*DIN
    if (idx >= DOUTP * DIN) return;
    int n = idx / DIN, k = idx - n * DIN;
    float v = (n < DOUT) ? W[k * DOUT + n] : 0.0f;
    Wt[idx] = (f16)v;
}

// ---------------- kernel 1: Wh = h@W + pos; f_src/f_dst partials; WhT ------
// grid 2048: strip = bid&1023 (64 rows), cs = bid>>10 (160-col half).
// 4 waves: rh = w&1 (32 rows), chf = w>>1 (5 col tiles of 16).
// Pipeline: B 2-ahead in LDS (3 buffers, DMA), A 3-deep in regs + 2 LDS bufs.
// Counted vmcnt so every waited-on load is >=2 iterations old.
__global__ __launch_bounds__(256, 3) void gemm1(
    const float* __restrict__ h, const f16* __restrict__ Wt,
    const int* __restrict__ positions,
    const float* __restrict__ a_src, const float* __restrict__ a_dst,
    const float* __restrict__ pos_table,
    f16* __restrict__ WhT, float* __restrict__ f_srcP, float* __restrict__ f_dstP)
{
    __shared__ f16 Al[2][64 * 40];      // A: 64 rows x 32 k, stride 40 f16
    __shared__ f16 Bl[3][DOUTC * 32];   // B: 160 n x 32 k, 10 KiB each (DMA dst)
    __shared__ float pfs[64][2], pfd[64][2];

    const int tid  = threadIdx.x;
    const int wave = tid >> 6, lane = tid & 63;
    const int quad = lane >> 4, c = lane & 15;
    const int rh  = wave & 1;
    const int chf = wave >> 1;           // 0..1 -> 5 tiles each
    const int strip = blockIdx.x & 1023;
    const int cs    = blockIdx.x >> 10;  // column half
    const int rowbase = strip * 64;
    const int colbase = cs * DOUTC;

    // B DMA: chunk = 16 rows x 32 k = 1024B; lane l -> row l>>2, slot l&3 (linear LDS dst);
    // source pre-swizzled: k-chunk j' = (l&3) ^ ((l>>3)&3)   [slot s of row r holds j = s^((r>>1)&3)]
    const int brow = lane >> 2;
    const int bj   = (lane & 3) ^ ((lane >> 3) & 3);
    const int ar = tid >> 2, aj = tid & 3;

    const float* abase = h + (size_t)(rowbase + ar) * DIN + aj * 8;

    f32x4 acc[2][5];
#pragma unroll
    for (int rt = 0; rt < 2; ++rt)
#pragma unroll
        for (int i = 0; i < 5; ++i) acc[rt][i] = (f32x4){0.f, 0.f, 0.f, 0.f};

    // waves 0,1 stage 3 chunks {w,w+4,w+8}; waves 2,3 stage 2 {w,w+4}
#define STAGE_B(K, BUF) do {                                                   \
    async_copy16((char*)Bl[(BUF)] + wave * 1024,                               \
        Wt + (size_t)(colbase + wave * 16 + brow) * DIN + (size_t)(K) * 32 + bj * 8); \
    async_copy16((char*)Bl[(BUF)] + (wave + 4) * 1024,                         \
        Wt + (size_t)(colbase + (wave + 4) * 16 + brow) * DIN + (size_t)(K) * 32 + bj * 8); \
    if (wave < 2)                                                              \
        async_copy16((char*)Bl[(BUF)] + (wave + 8) * 1024,                     \
            Wt + (size_t)(colbase + (wave + 8) * 16 + brow) * DIN + (size_t)(K) * 32 + bj * 8); \
} while (0)

#define LOAD_A(K, V0, V1) do {                                                 \
    const float4* s_ = (const float4*)(abase + (size_t)(K) * 32);              \
    V0 = s_[0]; V1 = s_[1]; } while (0)

#define WRITE_A(BUF, V0, V1)                                                   \
    *(f16x8*)&Al[(BUF)][ar * 40 + aj * 8] =                                    \
        (f16x8){(f16)V0.x, (f16)V0.y, (f16)V0.z, (f16)V0.w,                    \
                (f16)V1.x, (f16)V1.y, (f16)V1.z, (f16)V1.w}

#define COMPUTE(CB, CA) do {                                                   \
    f16x8 af0 = *(const f16x8*)&Al[(CA)][(rh * 32 + c) * 40 + quad * 8];       \
    f16x8 af1 = *(const f16x8*)&Al[(CA)][(rh * 32 + 16 + c) * 40 + quad * 8];  \
    _Pragma("unroll")                                                          \
    for (int i_ = 0; i_ < 5; ++i_) {                                           \
        int nl_ = (chf * 5 + i_) * 16 + c;                                     \
        f16x8 bf = *(const f16x8*)&Bl[(CB)][nl_ * 32 + (quad ^ ((nl_ >> 1) & 3)) * 8]; \
        acc[0][i_] = __builtin_amdgcn_mfma_f32_16x16x32_f16(af0, bf, acc[0][i_], 0, 0, 0); \
        acc[1][i_] = __builtin_amdgcn_mfma_f32_16x16x32_f16(af1, bf, acc[1][i_], 0, 0, 0); \
    } } while (0)

#define VMCNT_W(HI, LO) do {                                                   \
    if (wave < 2) { asm volatile("s_waitcnt vmcnt(" STR(HI) ")" ::: "memory"); } \
    else          { asm volatile("s_waitcnt vmcnt(" STR(LO) ")" ::: "memory"); } \
} while (0)

#define ITER(KT, CB, NB, CA, PFB, PFA, LV0, LV1, WA, WV0, WV1, BAR, VH, VL) do { \
    if (PFB) { STAGE_B((KT) + 2, NB); }                                        \
    if (PFA) { LOAD_A((KT) + 3, LV0, LV1); }                                   \
    COMPUTE(CB, CA);                                                           \
    if (WA)  { WRITE_A((CA) ^ 1, WV0, WV1); }                                  \
    if (BAR) { VMCNT_W(VH, VL);                                                \
               asm volatile("s_waitcnt lgkmcnt(0)" ::: "memory");              \
               __builtin_amdgcn_s_barrier();                                   \
               asm volatile("" ::: "memory"); }                                \
} while (0)

    float4 s0a, s0b, s1a, s1b, s2a, s2b;   // A reg sets, depth 3

    // ---- prologue: B0,B1 in flight; A0,A1,A2 in regs; A0 -> LDS ----
    STAGE_B(0, 0); LOAD_A(0, s0a, s0b);
    asm volatile("" ::: "memory");
    STAGE_B(1, 1); LOAD_A(1, s1a, s1b); LOAD_A(2, s2a, s2b);
    WRITE_A(0, s0a, s0b);                 // implicit wait covers A0 and (older) B0
    asm volatile("s_waitcnt lgkmcnt(0)" ::: "memory");
    __builtin_amdgcn_s_barrier();
    asm volatile("" ::: "memory");

    // KT=0: prologue issued A1,A2 after B1 -> vmcnt 9/8 this once
    ITER(0, 0, 2, 0, 1, 1, s0a, s0b, 1, s1a, s1b, 1, 9, 8);
    for (int kb = 1; kb < 19; kb += 6) {
        ITER(kb + 0, 1, 0, 1, 1, 1, s1a, s1b, 1, s2a, s2b, 1, 7, 6);
        ITER(kb + 1, 2, 1, 0, 1, 1, s2a, s2b, 1, s0a, s0b, 1, 7, 6);
        ITER(kb + 2, 0, 2, 1, 1, 1, s0a, s0b, 1, s1a, s1b, 1, 7, 6);
        ITER(kb + 3, 1, 0, 0, 1, 1, s1a, s1b, 1, s2a, s2b, 1, 7, 6);
        ITER(kb + 4, 2, 1, 1, 1, 1, s2a, s2b, 1, s0a, s0b, 1, 7, 6);
        ITER(kb + 5, 0, 2, 0, 1, 1, s0a, s0b, 1, s1a, s1b, 1, 7, 6);
    }
    ITER(19, 1, 0, 1, 1, 1, s1a, s1b, 1, s2a, s2b, 1, 7, 6);
    ITER(20, 2, 1, 0, 1, 1, s2a, s2b, 1, s0a, s0b, 1, 7, 6);  // loads A23 -> set2
    ITER(21, 0, 2, 1, 1, 0, s0a, s0b, 1, s1a, s1b, 1, 5, 4);  // stage B23; write A22
    ITER(22, 1, 0, 0, 0, 0, s0a, s0b, 1, s2a, s2b, 1, 0, 0);  // drain; write A23
    ITER(23, 2, 0, 1, 0, 0, s0a, s0b, 0, s0a, s0b, 0, 0, 0);  // last, no barrier

#undef ITER
#undef VMCNT_W
#undef COMPUTE
#undef WRITE_A
#undef LOAD_A
#undef STAGE_B

    // ---- epilogue: pos add, f_src/f_dst partials, WhT store ----
    const int bidx  = rowbase >> 8;
    const int mloc  = (rowbase & 255);

    int posr[2][4];
#pragma unroll
    for (int rt = 0; rt < 2; ++rt)
#pragma unroll
        for (int r = 0; r < 4; ++r)
            posr[rt][r] = positions[rowbase + rh * 32 + rt * 16 + quad * 4 + r];

    float fs[2][4] = {{0,0,0,0},{0,0,0,0}}, fd[2][4] = {{0,0,0,0},{0,0,0,0}};
#pragma unroll
    for (int i = 0; i < 5; ++i) {
        int col = colbase + (chf * 5 + i) * 16 + c;
        if (col < DOUT) {
            float as = a_src[col], ad = a_dst[col];
#pragma unroll
            for (int rt = 0; rt < 2; ++rt)
#pragma unroll
                for (int r = 0; r < 4; ++r) {
                    float v = acc[rt][i][r] + pos_table[posr[rt][r] * DOUT + col];
                    acc[rt][i][r] = v;
                    fs[rt][r] += v * as;
                    fd[rt][r] += v * ad;
                }
        } else {
#pragma unroll
            for (int rt = 0; rt < 2; ++rt)
#pragma unroll
                for (int r = 0; r < 4; ++r) acc[rt][i][r] = 0.0f;
        }
    }
#pragma unroll
    for (int off = 1; off < 16; off <<= 1) {
#pragma unroll
        for (int rt = 0; rt < 2; ++rt)
#pragma unroll
            for (int r = 0; r < 4; ++r) {
                fs[rt][r] += __shfl_xor(fs[rt][r], off, 16);
                fd[rt][r] += __shfl_xor(fd[rt][r], off, 16);
            }
    }
    if (c == 0) {
#pragma unroll
        for (int rt = 0; rt < 2; ++rt)
#pragma unroll
            for (int r = 0; r < 4; ++r) {
                int row = rh * 32 + rt * 16 + quad * 4 + r;
                pfs[row][chf] = fs[rt][r];
                pfd[row][chf] = fd[rt][r];
            }
    }
    // WhT[b][col][m] fp16
#pragma unroll
    for (int i = 0; i < 5; ++i) {
        int col = colbase + (chf * 5 + i) * 16 + c;
#pragma unroll
        for (int rt = 0; rt < 2; ++rt) {
            int mrow = mloc + rh * 32 + rt * 16 + quad * 4;
            f16x4 u = (f16x4){(f16)acc[rt][i][0], (f16)acc[rt][i][1],
                              (f16)acc[rt][i][2], (f16)acc[rt][i][3]};
            *(f16x4*)(WhT + ((size_t)bidx * DOUTP + col) * N_ + mrow) = u;
        }
    }
    __syncthreads();
    if (tid < 64) {
        f_srcP[(size_t)cs * M_ + rowbase + tid] = pfs[tid][0] + pfs[tid][1];
        f_dstP[(size_t)cs * M_ + rowbase + tid] = pfd[tid][0] + pfd[tid][1];
    }
}

// ---------------- kernel 2: fused masked-softmax + h_prime = att @ Wh ------
// grid 1024 (64 rows/block), 256 threads.
__global__ __launch_bounds__(256, 2) void fused2(
    const float* __restrict__ adj, const float* __restrict__ f_srcP,
    const float* __restrict__ f_dstP, const f16* __restrict__ WhT,
    float* __restrict__ att, float* __restrict__ hp)
{
    __shared__ f16 Pl[64 * 264];        // P: 64 rows x 256 k, stride 264 f16
    __shared__ f16 Bl[2][DOUTP * 32];

    const int tid  = threadIdx.x;
    const int wave = tid >> 6, lane = tid & 63;
    const int quad = lane >> 4, c = lane & 15;
    const int rh = wave & 1;
    const int chf = wave >> 1;
    const int rowbase = blockIdx.x * 64;
    const int bidx = rowbase >> 8;

    const int brow = lane >> 2;
    const int bj   = (lane & 3) ^ ((lane >> 3) & 3);

#define STAGE_B2(K, BUF) do {                                                  \
    _Pragma("unroll")                                                          \
    for (int i_ = 0; i_ < 5; ++i_) {                                           \
        int chk_ = wave + 4 * i_;                                              \
        int n_ = chk_ * 16 + brow;                                             \
        async_copy16((char*)Bl[(BUF)] + chk_ * 1024,                           \
                     WhT + ((size_t)bidx * DOUTP + n_) * N_ + (size_t)(K) * 32 + bj * 8); \
    } } while (0)

    // B tiles 0,1 in flight under the softmax phase
    STAGE_B2(0, 0);
    STAGE_B2(1, 1);

    // ---- phase 0: masked softmax for 64 rows; att out + P into LDS ----
    {
        float4 fdA = *(const float4*)(f_dstP + bidx * N_ + lane * 4);
        float4 fdB = *(const float4*)(f_dstP + M_ + bidx * N_ + lane * 4);
        float4 fd4 = make_float4(fdA.x + fdB.x, fdA.y + fdB.y,
                                 fdA.z + fdB.z, fdA.w + fdB.w);
        const float* arow = adj + (size_t)(rowbase + wave * 16) * N_ + lane * 4;
        float4 nx0 = *(const float4*)arow;
        float4 nx1 = *(const float4*)(arow + N_);
        for (int rr = 0; rr < 16; ++rr) {
            float4 a4 = nx0;
            nx0 = nx1;
            if (rr + 2 < 16) nx1 = *(const float4*)(arow + (size_t)(rr + 2) * N_);
            const int lrow = wave * 16 + rr;
            const int row  = rowbase + lrow;
            float fs = f_srcP[row] + f_srcP[M_ + row];

            float v, e0, e1, e2, e3;
            v = fs + fd4.x; v = v >= 0.f ? v : 0.2f * v; e0 = a4.x > 0.f ? v : NEG_INF;
            v = fs + fd4.y; v = v >= 0.f ? v : 0.2f * v; e1 = a4.y > 0.f ? v : NEG_INF;
            v = fs + fd4.z; v = v >= 0.f ? v : 0.2f * v; e2 = a4.z > 0.f ? v : NEG_INF;
            v = fs + fd4.w; v = v >= 0.f ? v : 0.2f * v; e3 = a4.w > 0.f ? v : NEG_INF;

            float mx = fmaxf(fmaxf(e0, e1), fmaxf(e2, e3));
#pragma unroll
            for (int off = 1; off < 64; off <<= 1) mx = fmaxf(mx, __shfl_xor(mx, off, 64));

            float p0 = __expf(e0 - mx), p1 = __expf(e1 - mx);
            float p2 = __expf(e2 - mx), p3 = __expf(e3 - mx);
            float s = p0 + p1 + p2 + p3;
#pragma unroll
            for (int off = 1; off < 64; off <<= 1) s += __shfl_xor(s, off, 64);

            float inv = 1.0f / s;
            *(float4*)(att + (size_t)row * N_ + lane * 4) =
                make_float4(p0 * inv, p1 * inv, p2 * inv, p3 * inv);
            *(f16x4*)&Pl[lrow * 264 + lane * 4] =
                (f16x4){(f16)(p0 * inv), (f16)(p1 * inv), (f16)(p2 * inv), (f16)(p3 * inv)};
        }
    }
    __syncthreads();   // P visible; B tiles 0,1 landed

    // ---- phase 1: GEMM, A = P (LDS-resident), B 1-ahead double-buffer ----
    f32x4 acc[2][10];
#pragma unroll
    for (int rt = 0; rt < 2; ++rt)
#pragma unroll
        for (int i = 0; i < 10; ++i) acc[rt][i] = (f32x4){0.f, 0.f, 0.f, 0.f};

#pragma unroll
    for (int kt = 0; kt < 8; ++kt) {
        f16x8 af0 = *(const f16x8*)&Pl[(rh * 32 + c) * 264 + kt * 32 + quad * 8];
        f16x8 af1 = *(const f16x8*)&Pl[(rh * 32 + 16 + c) * 264 + kt * 32 + quad * 8];
#pragma unroll
        for (int i = 0; i < 10; ++i) {
            int n = (chf * 10 + i) * 16 + c;
            f16x8 bf = *(const f16x8*)&Bl[kt & 1][n * 32 + (quad ^ ((n >> 1) & 3)) * 8];
            acc[0][i] = __builtin_amdgcn_mfma_f32_16x16x32_f16(af0, bf, acc[0][i], 0, 0, 0);
            acc[1][i] = __builtin_amdgcn_mfma_f32_16x16x32_f16(af1, bf, acc[1][i], 0, 0, 0);
        }
        if (kt < 7) {
            __syncthreads();                    // reads of Bl[kt&1] done; tile kt+1 landed
            if (kt + 2 < 8) STAGE_B2(kt + 2, kt & 1);
        }
    }
#undef STAGE_B2

    // epilogue: hp[row][col], col<300
#pragma unroll
    for (int i = 0; i < 10; ++i) {
        int col = (chf * 10 + i) * 16 + c;
        if (col < DOUT) {
#pragma unroll
            for (int rt = 0; rt < 2; ++rt) {
                int row0 = rowbase + rh * 32 + rt * 16 + quad * 4;
#pragma unroll
                for (int r = 0; r < 4; ++r)
                    hp[(size_t)(row0 + r) * DOUT + col] = acc[rt][i][r];
            }
        }
    }
}

extern "C" void kernel_launch(void* const* d_in, const int* in_sizes, int n_in,
                              void* d_out, int out_size, void* d_ws, size_t ws_size,
                              hipStream_t stream)
{
    const float* h         = (const float*)d_in[0];
    const float* adj       = (const float*)d_in[1];
    const int*   positions = (const int*)d_in[2];
    const float* W         = (const float*)d_in[3];
    const float* a_src     = (const float*)d_in[4];
    const float* a_dst     = (const float*)d_in[5];
    const float* pos_table = (const float*)d_in[6];

    float* hp  = (float*)d_out;            // [65536][300]
    float* att = hp + HP_ELEMS;            // [65536][256]

    f16*   Wt     = (f16*)d_ws;                        // 320*768
    f16*   WhT    = Wt + (size_t)DOUTP * DIN;          // 256*320*256
    float* f_srcP = (float*)(WhT + (size_t)B_ * DOUTP * N_);   // [2][65536]
    float* f_dstP = f_srcP + 2 * (size_t)M_;                   // [2][65536]

    hipLaunchKernelGGL(prep_wt, dim3((DOUTP * DIN + 255) / 256), dim3(256), 0, stream, W, Wt);
    hipLaunchKernelGGL(gemm1,   dim3(2 * M_ / 64), dim3(256), 0, stream,
                       h, Wt, positions, a_src, a_dst, pos_table, WhT, f_srcP, f_dstP);
    hipLaunchKernelGGL(fused2,  dim3(M_ / 64), dim3(256), 0, stream,
                       adj, f_srcP, f_dstP, WhT, att, hp);
}

// Round 3
// 455.661 us; speedup vs baseline: 1.0517x; 1.0517x over previous
//
#include <hip/hip_runtime.h>

#define B_    256
#define N_    256
#define DIN   768
#define DOUT  300
#define DOUTP 320           // padded to 20*16
#define M_    (B_*N_)       // 65536
#define HP_ELEMS (M_*DOUT)  // 19660800
#define NEG_INF -9.0e15f

typedef _Float16 f16;
typedef __attribute__((ext_vector_type(8))) _Float16 f16x8;
typedef __attribute__((ext_vector_type(4))) _Float16 f16x4;
typedef __attribute__((ext_vector_type(4))) float    f32x4;

__device__ __forceinline__ void async_copy16(void* lds, const void* g) {
    __builtin_amdgcn_global_load_lds(
        (const __attribute__((address_space(1))) void*)g,
        (__attribute__((address_space(3))) void*)lds, 16, 0, 0);
}

// ---- kernel 0: WtT[kt][n][32] = f16(W[k][n]), k-tiled, k-slot pre-swizzled,
//      zero-pad n>=300. Slot swizzle: physical slot = (k>>3 & 3) ^ ((n>>1)&3).
__global__ __launch_bounds__(256) void prep_wt(const float* __restrict__ W,
                                               f16* __restrict__ WtT) {
    int idx = blockIdx.x * 256 + threadIdx.x;      // over DIN*DOUTP
    if (idx >= DIN * DOUTP) return;
    int k = idx / DOUTP, n = idx - k * DOUTP;      // consecutive tid -> consecutive n
    float v = (n < DOUT) ? W[k * DOUT + n] : 0.0f;
    int kt = k >> 5, sl = ((k >> 3) & 3) ^ ((n >> 1) & 3), e = k & 7;
    WtT[(((size_t)kt * DOUTP + n) << 5) + (sl << 3) + e] = (f16)v;
}

// ---- kernel 1: Wh = h@W + pos; f_src/f_dst; WhT2 (k-tiled, pre-swizzled) ----
// grid 2048 strips of 32 rows, 256 threads (4 waves), 3 blocks/CU.
// A: converted f32->f16 into LDS once per K-half (12 kt). B: pure
// global_load_lds from contiguous WtT tiles, single buffer, vmcnt(0)+barrier
// per K-step; latency covered by 3 resident blocks.
__global__ __launch_bounds__(256, 3) void gemm1(
    const float* __restrict__ h, const f16* __restrict__ WtT,
    const int* __restrict__ positions,
    const float* __restrict__ a_src, const float* __restrict__ a_dst,
    const float* __restrict__ pos_table,
    f16* __restrict__ WhT2, float* __restrict__ f_src, float* __restrict__ f_dst)
{
    __shared__ f16 Ah[32 * 384];       // 24 KB: 32 rows x 12kt x 32, XOR-swizzled
    __shared__ f16 Bs[DOUTP * 32];     // 20 KB: one k-tile of WtT (linear DMA copy)
    __shared__ float pfs[32][4], pfd[32][4];

    const int tid  = threadIdx.x;
    const int wave = tid >> 6, lane = tid & 63;
    const int quad = lane >> 4, c = lane & 15;
    const int rowbase = blockIdx.x * 32;

    // convert-phase mapping: thread -> (row, 8-lane k-slice)
    const int crow = tid >> 3, cl8 = tid & 7;
    const float* cbase = h + (size_t)(rowbase + crow) * DIN;

    // B fragment offsets (f16 elements) — loop-invariant (single buffer)
    int boff[5];
#pragma unroll
    for (int i = 0; i < 5; ++i) {
        int n = (wave * 5 + i) * 16 + c;
        boff[i] = n * 32 + ((quad ^ ((n >> 1) & 3)) << 3);
    }
    const int arow0 = c * 384, arow1 = (16 + c) * 384;   // f16 row bases
    const int cx7 = c & 7;

    f32x4 acc[2][5];
#pragma unroll
    for (int rt = 0; rt < 2; ++rt)
#pragma unroll
        for (int i = 0; i < 5; ++i) acc[rt][i] = (f32x4){0.f, 0.f, 0.f, 0.f};

    for (int half = 0; half < 2; ++half) {
        // ---- convert 32 rows x 384 f32 -> Ah (f16, swizzled) ----
#pragma unroll
        for (int j = 0; j < 6; ++j) {
            int c8 = j * 8 + cl8;                       // 0..47 (16B chunk idx)
            const float4* s = (const float4*)(cbase + half * 384 + c8 * 8);
            float4 v0 = s[0], v1 = s[1];
            int slot = c8 ^ (crow & 7);
            *(f16x8*)&Ah[crow * 384 + slot * 8] =
                (f16x8){(f16)v0.x, (f16)v0.y, (f16)v0.z, (f16)v0.w,
                        (f16)v1.x, (f16)v1.y, (f16)v1.z, (f16)v1.w};
        }
        __syncthreads();

#pragma unroll
        for (int kt12 = 0; kt12 < 12; ++kt12) {
            const int kt = half * 12 + kt12;
            // stage B tile kt (linear contiguous: 20 chunks of 1KB, 5/wave)
#pragma unroll
            for (int i = 0; i < 5; ++i) {
                int chk = wave * 5 + i;
                async_copy16((char*)Bs + chk * 1024,
                             (const char*)WtT + (size_t)kt * 20480 + chk * 1024 + lane * 16);
            }
            __builtin_amdgcn_sched_barrier(0);
            asm volatile("s_waitcnt vmcnt(0)");
            __builtin_amdgcn_sched_barrier(0);
            __builtin_amdgcn_s_barrier();              // all chunks visible
            __builtin_amdgcn_sched_barrier(0);

            int k4 = kt12 * 4 + quad;
            f16x8 af0 = *(const f16x8*)&Ah[arow0 + ((k4 ^ cx7) << 3)];
            f16x8 af1 = *(const f16x8*)&Ah[arow1 + ((k4 ^ cx7) << 3)];
            __builtin_amdgcn_s_setprio(1);
#pragma unroll
            for (int i = 0; i < 5; ++i) {
                f16x8 bf = *(const f16x8*)&Bs[boff[i]];
                acc[0][i] = __builtin_amdgcn_mfma_f32_16x16x32_f16(af0, bf, acc[0][i], 0, 0, 0);
                acc[1][i] = __builtin_amdgcn_mfma_f32_16x16x32_f16(af1, bf, acc[1][i], 0, 0, 0);
            }
            __builtin_amdgcn_s_setprio(0);
            __builtin_amdgcn_sched_barrier(0);
            __builtin_amdgcn_s_barrier();              // reads of Bs done
            __builtin_amdgcn_sched_barrier(0);
        }
    }

    // ---- epilogue: pos add, f_src/f_dst, WhT2 store (k-tiled + swizzled) ----
    const int bidx = rowbase >> 8;
    const int ktb  = (rowbase & 255) >> 5;

    int posr[2][4];
#pragma unroll
    for (int rt = 0; rt < 2; ++rt)
#pragma unroll
        for (int r = 0; r < 4; ++r)
            posr[rt][r] = positions[rowbase + rt * 16 + quad * 4 + r];

    float fs[2][4] = {{0,0,0,0},{0,0,0,0}}, fd[2][4] = {{0,0,0,0},{0,0,0,0}};
#pragma unroll
    for (int i = 0; i < 5; ++i) {
        int col = (wave * 5 + i) * 16 + c;
        if (col < DOUT) {
            float as = a_src[col], ad = a_dst[col];
#pragma unroll
            for (int rt = 0; rt < 2; ++rt)
#pragma unroll
                for (int r = 0; r < 4; ++r) {
                    float v = acc[rt][i][r] + pos_table[posr[rt][r] * DOUT + col];
                    acc[rt][i][r] = v;
                    fs[rt][r] += v * as;
                    fd[rt][r] += v * ad;
                }
        } else {
#pragma unroll
            for (int rt = 0; rt < 2; ++rt)
#pragma unroll
                for (int r = 0; r < 4; ++r) acc[rt][i][r] = 0.0f;
        }
    }
#pragma unroll
    for (int off = 1; off < 16; off <<= 1) {
#pragma unroll
        for (int rt = 0; rt < 2; ++rt)
#pragma unroll
            for (int r = 0; r < 4; ++r) {
                fs[rt][r] += __shfl_xor(fs[rt][r], off, 16);
                fd[rt][r] += __shfl_xor(fd[rt][r], off, 16);
            }
    }
    if (c == 0) {
#pragma unroll
        for (int rt = 0; rt < 2; ++rt)
#pragma unroll
            for (int r = 0; r < 4; ++r) {
                int row = rt * 16 + quad * 4 + r;
                pfs[row][wave] = fs[rt][r];
                pfd[row][wave] = fd[rt][r];
            }
    }
    // WhT2[bidx][ktb][col][32]: f16x4 at swizzled slot
#pragma unroll
    for (int i = 0; i < 5; ++i) {
        int col = (wave * 5 + i) * 16 + c;
#pragma unroll
        for (int rt = 0; rt < 2; ++rt) {
            f16x4 u = (f16x4){(f16)acc[rt][i][0], (f16)acc[rt][i][1],
                              (f16)acc[rt][i][2], (f16)acc[rt][i][3]};
            int sl = (rt * 2 + (quad >> 1)) ^ ((col >> 1) & 3);
            *(f16x4*)(WhT2 + (((size_t)(bidx * 8 + ktb) * DOUTP + col) << 5)
                           + (sl << 3) + ((quad & 1) << 2)) = u;
        }
    }
    __syncthreads();
    if (tid < 32) {
        f_src[rowbase + tid] = pfs[tid][0] + pfs[tid][1] + pfs[tid][2] + pfs[tid][3];
        f_dst[rowbase + tid] = pfd[tid][0] + pfd[tid][1] + pfd[tid][2] + pfd[tid][3];
    }
}

// ---- kernel 2: fused masked-softmax + h_prime = att @ Wh ------------------
// grid 1024 (64 rows/block), 256 threads, 2 blocks/CU.
// B from k-tiled pre-swizzled WhT2 (linear contiguous DMA), staged 1.5 iters
// ahead with counted vmcnt(5). P kept in swizzled LDS f16.
__global__ __launch_bounds__(256, 2) void fused2(
    const float* __restrict__ adj, const float* __restrict__ f_src,
    const float* __restrict__ f_dst, const f16* __restrict__ WhT2,
    float* __restrict__ att, float* __restrict__ hp)
{
    __shared__ f16 Pl[64 * 256];        // 32 KB, XOR-swizzled
    __shared__ f16 Bl[2][DOUTP * 32];   // 2 x 20 KB

    const int tid  = threadIdx.x;
    const int wave = tid >> 6, lane = tid & 63;
    const int quad = lane >> 4, c = lane & 15;
    const int rh = wave & 1;
    const int chf = wave >> 1;
    const int rowbase = blockIdx.x * 64;
    const int bidx = rowbase >> 8;

#define STAGE_B2(K, BUF) do {                                                  \
    _Pragma("unroll")                                                          \
    for (int i_ = 0; i_ < 5; ++i_) {                                           \
        int chk_ = wave * 5 + i_;                                              \
        async_copy16((char*)Bl[(BUF)] + chk_ * 1024,                           \
                     (const char*)WhT2 + (size_t)(bidx * 8 + (K)) * 20480      \
                                       + chk_ * 1024 + lane * 16);             \
    } } while (0)

    // B tiles 0,1 in flight under the softmax phase
    STAGE_B2(0, 0);
    STAGE_B2(1, 1);

    // ---- phase 0: masked softmax for 64 rows; att out + P into LDS ----
    {
        float4 fd4 = *(const float4*)(f_dst + bidx * N_ + lane * 4);
        const float* arow = adj + (size_t)(rowbase + wave * 16) * N_ + lane * 4;
        float4 nx0 = *(const float4*)arow;
        float4 nx1 = *(const float4*)(arow + N_);
        for (int rr = 0; rr < 16; ++rr) {
            float4 a4 = nx0;
            nx0 = nx1;
            if (rr + 2 < 16) nx1 = *(const float4*)(arow + (size_t)(rr + 2) * N_);
            const int lrow = wave * 16 + rr;
            const int row  = rowbase + lrow;
            float fsv = f_src[row];

            float v, e0, e1, e2, e3;
            v = fsv + fd4.x; v = v >= 0.f ? v : 0.2f * v; e0 = a4.x > 0.f ? v : NEG_INF;
            v = fsv + fd4.y; v = v >= 0.f ? v : 0.2f * v; e1 = a4.y > 0.f ? v : NEG_INF;
            v = fsv + fd4.z; v = v >= 0.f ? v : 0.2f * v; e2 = a4.z > 0.f ? v : NEG_INF;
            v = fsv + fd4.w; v = v >= 0.f ? v : 0.2f * v; e3 = a4.w > 0.f ? v : NEG_INF;

            float mx = fmaxf(fmaxf(e0, e1), fmaxf(e2, e3));
#pragma unroll
            for (int off = 1; off < 64; off <<= 1) mx = fmaxf(mx, __shfl_xor(mx, off, 64));

            float p0 = __expf(e0 - mx), p1 = __expf(e1 - mx);
            float p2 = __expf(e2 - mx), p3 = __expf(e3 - mx);
            float s = p0 + p1 + p2 + p3;
#pragma unroll
            for (int off = 1; off < 64; off <<= 1) s += __shfl_xor(s, off, 64);

            float inv = 1.0f / s;
            *(float4*)(att + (size_t)row * N_ + lane * 4) =
                make_float4(p0 * inv, p1 * inv, p2 * inv, p3 * inv);
            // P swizzled: chunk = lane>>1 (16B), half = lane&1
            int slot = (lane >> 1) ^ (lrow & 7);
            *(f16x4*)&Pl[lrow * 256 + slot * 8 + (lane & 1) * 4] =
                (f16x4){(f16)(p0 * inv), (f16)(p1 * inv), (f16)(p2 * inv), (f16)(p3 * inv)};
        }
    }
    __syncthreads();   // P visible; B tiles 0,1 landed (full drain)

    // ---- phase 1: GEMM, A = P (LDS), B 1.5-ahead with counted vmcnt ----
    f32x4 acc[2][10];
#pragma unroll
    for (int rt = 0; rt < 2; ++rt)
#pragma unroll
        for (int i = 0; i < 10; ++i) acc[rt][i] = (f32x4){0.f, 0.f, 0.f, 0.f};

    const int ar0 = (rh * 32 + c) * 256, ar1 = (rh * 32 + 16 + c) * 256;
    const int cx7 = c & 7;

#pragma unroll
    for (int kt = 0; kt < 8; ++kt) {
        int k4 = kt * 4 + quad;
        f16x8 af0 = *(const f16x8*)&Pl[ar0 + ((k4 ^ cx7) << 3)];
        f16x8 af1 = *(const f16x8*)&Pl[ar1 + ((k4 ^ cx7) << 3)];
        __builtin_amdgcn_s_setprio(1);
#pragma unroll
        for (int i = 0; i < 10; ++i) {
            int n = (chf * 10 + i) * 16 + c;
            f16x8 bf = *(const f16x8*)&Bl[kt & 1][n * 32 + ((quad ^ ((n >> 1) & 3)) << 3)];
            acc[0][i] = __builtin_amdgcn_mfma_f32_16x16x32_f16(af0, bf, acc[0][i], 0, 0, 0);
            acc[1][i] = __builtin_amdgcn_mfma_f32_16x16x32_f16(af1, bf, acc[1][i], 0, 0, 0);
        }
        __builtin_amdgcn_s_setprio(0);
        if (kt < 7) {
            __builtin_amdgcn_sched_barrier(0);
            __builtin_amdgcn_s_barrier();          // reads of Bl[kt&1] done
            __builtin_amdgcn_sched_barrier(0);
            if (kt + 2 < 8) {
                STAGE_B2(kt + 2, kt & 1);
                __builtin_amdgcn_sched_barrier(0);
                asm volatile("s_waitcnt vmcnt(5)"); // B[kt+1] landed
            } else {
                __builtin_amdgcn_sched_barrier(0);
                asm volatile("s_waitcnt vmcnt(0)");
            }
            __builtin_amdgcn_sched_barrier(0);
            __builtin_amdgcn_s_barrier();          // all waves' waits done
            __builtin_amdgcn_sched_barrier(0);
        }
    }
#undef STAGE_B2

    // epilogue: hp[row][col], col<300
#pragma unroll
    for (int i = 0; i < 10; ++i) {
        int col = (chf * 10 + i) * 16 + c;
        if (col < DOUT) {
#pragma unroll
            for (int rt = 0; rt < 2; ++rt) {
                int row0 = rowbase + rh * 32 + rt * 16 + quad * 4;
#pragma unroll
                for (int r = 0; r < 4; ++r)
                    hp[(size_t)(row0 + r) * DOUT + col] = acc[rt][i][r];
            }
        }
    }
}

extern "C" void kernel_launch(void* const* d_in, const int* in_sizes, int n_in,
                              void* d_out, int out_size, void* d_ws, size_t ws_size,
                              hipStream_t stream)
{
    const float* h         = (const float*)d_in[0];
    const float* adj       = (const float*)d_in[1];
    const int*   positions = (const int*)d_in[2];
    const float* W         = (const float*)d_in[3];
    const float* a_src     = (const float*)d_in[4];
    const float* a_dst     = (const float*)d_in[5];
    const float* pos_table = (const float*)d_in[6];

    float* hp  = (float*)d_out;            // [65536][300]
    float* att = hp + HP_ELEMS;            // [65536][256]

    f16*   WtT   = (f16*)d_ws;                         // [24][320][32]
    f16*   WhT2  = WtT + (size_t)DOUTP * DIN;          // [256*8][320][32]
    float* f_src = (float*)(WhT2 + (size_t)B_ * DOUTP * N_);
    float* f_dst = f_src + M_;

    hipLaunchKernelGGL(prep_wt, dim3((DIN * DOUTP + 255) / 256), dim3(256), 0, stream, W, WtT);
    hipLaunchKernelGGL(gemm1,   dim3(M_ / 32), dim3(256), 0, stream,
                       h, WtT, positions, a_src, a_dst, pos_table, WhT2, f_src, f_dst);
    hipLaunchKernelGGL(fused2,  dim3(M_ / 64), dim3(256), 0, stream,
                       adj, f_src, f_dst, WhT2, att, hp);
}